// Round 9
// baseline (4617.102 us; speedup 1.0000x reference)
//
#include <hip/hip_runtime.h>
#include <math.h>

#define NB 256
#define NH 512
#define NIN 512
#define NT 128
#define NG 2048   // 4*H gate rows

typedef __attribute__((ext_vector_type(4))) float f32x4;

// Persistent state in module data segment — capture-safe, ws-independent.
__device__ float g_h0[NB * NH];
__device__ float g_h1[NB * NH];
// Hoisted input projection xg[t][b][g] = chain_k x[t][b][k]*w_ih[g][k]  (256 MB)
// ORIGINAL layout: g_xg[(t*NB + b)*NG + q*NH + j]   (proven v6)
__device__ float g_xg[(size_t)NT * NB * NG];
// Per-block barrier flags, one 128B line each (monotonic step values).
#define FLAG_STRIDE 32
__device__ int g_flags[256 * FLAG_STRIDE];

// LDS layout for the persistent kernel
#define WSTR 516                     // 512 + 4 pad  (stride%32==4 -> 2-way = free)
#define HSTR 68                      // 64 + 4 pad
#define LDS_WF (64 * WSTR)           // persistent W tile, floats
#define LDS_HF (2 * 32 * HSTR)       // double-buffered H chunk, floats
#define LDS_BYTES ((LDS_WF + LDS_HF) * 4)   // 149504 B < 160 KiB/CU

// ---------------------------------------------------------------------------
__global__ __launch_bounds__(256) void zero_state() {
    int i = blockIdx.x * 256 + threadIdx.x;   // grid 512*256 = NB*NH
    g_h0[i] = 0.f;
    if (i < 256 * FLAG_STRIDE) g_flags[i] = 0;
}

// ---------------------------------------------------------------------------
// xg = x @ w_ih^T  : M=NT*NB=32768, N=NG=2048, K=512.  (proven-exact original)
#define BM 128
#define BN 128
#define BK 16

__global__ __launch_bounds__(256, 2) void xg_gemm(
    const float* __restrict__ x,      // [M][512]
    const float* __restrict__ w_ih)   // [2048][512]
{
    __shared__ float As[2][BK][BM + 4];
    __shared__ float Bs[2][BK][BN + 4];

    const int tid = threadIdx.x;
    const int bm = blockIdx.x >> 4;
    const int bn = blockIdx.x & 15;
    const size_t m0 = (size_t)bm * BM;
    const int n0 = bn * BN;

    const int srow = tid >> 1;
    const int sc4  = (tid & 1) * 8;
    const float* __restrict__ Arow = x    + (m0 + srow) * NIN;
    const float* __restrict__ Brow = w_ih + (size_t)(n0 + srow) * NIN;

    const int tx = tid & 15;
    const int ty = tid >> 4;

    float acc[8][8];
    #pragma unroll
    for (int i = 0; i < 8; ++i)
        #pragma unroll
        for (int j = 0; j < 8; ++j) acc[i][j] = 0.f;

    float4 ar0, ar1, br0, br1;

#define LOAD_TILE(kb) do {                                   \
        ar0 = *(const float4*)(Arow + (kb) + sc4);           \
        ar1 = *(const float4*)(Arow + (kb) + sc4 + 4);       \
        br0 = *(const float4*)(Brow + (kb) + sc4);           \
        br1 = *(const float4*)(Brow + (kb) + sc4 + 4);       \
    } while (0)

#define STORE_TILE(buf) do {                                             \
        As[buf][sc4+0][srow] = ar0.x; As[buf][sc4+1][srow] = ar0.y;      \
        As[buf][sc4+2][srow] = ar0.z; As[buf][sc4+3][srow] = ar0.w;      \
        As[buf][sc4+4][srow] = ar1.x; As[buf][sc4+5][srow] = ar1.y;      \
        As[buf][sc4+6][srow] = ar1.z; As[buf][sc4+7][srow] = ar1.w;      \
        Bs[buf][sc4+0][srow] = br0.x; Bs[buf][sc4+1][srow] = br0.y;      \
        Bs[buf][sc4+2][srow] = br0.z; Bs[buf][sc4+3][srow] = br0.w;      \
        Bs[buf][sc4+4][srow] = br1.x; Bs[buf][sc4+5][srow] = br1.y;      \
        Bs[buf][sc4+6][srow] = br1.z; Bs[buf][sc4+7][srow] = br1.w;      \
    } while (0)

    auto mk = [&](int buf) {
        #pragma unroll
        for (int k = 0; k < BK; ++k) {
            const float4 a0 = *(const float4*)(&As[buf][k][ty * 4]);
            const float4 a1 = *(const float4*)(&As[buf][k][64 + ty * 4]);
            const float4 b0 = *(const float4*)(&Bs[buf][k][tx * 4]);
            const float4 b1 = *(const float4*)(&Bs[buf][k][64 + tx * 4]);
            const float av[8] = {a0.x, a0.y, a0.z, a0.w, a1.x, a1.y, a1.z, a1.w};
            const float bv[8] = {b0.x, b0.y, b0.z, b0.w, b1.x, b1.y, b1.z, b1.w};
            #pragma unroll
            for (int i = 0; i < 8; ++i)
                #pragma unroll
                for (int j = 0; j < 8; ++j)
                    acc[i][j] = fmaf(av[i], bv[j], acc[i][j]);
        }
    };

    LOAD_TILE(0);
    STORE_TILE(0);
    __syncthreads();
    for (int tt = 0; tt < 31; ++tt) {
        LOAD_TILE((tt + 1) * BK);
        mk(tt & 1);
        STORE_TILE((tt + 1) & 1);
        __syncthreads();
    }
    mk(1);

    #pragma unroll
    for (int i = 0; i < 8; ++i) {
        const int mr = (i < 4) ? (ty * 4 + i) : (64 + ty * 4 + i - 4);
        float* __restrict__ orow = g_xg + (m0 + mr) * NG + n0;
        *(float4*)(orow + tx * 4)      = make_float4(acc[i][0], acc[i][1], acc[i][2], acc[i][3]);
        *(float4*)(orow + 64 + tx * 4) = make_float4(acc[i][4], acc[i][5], acc[i][6], acc[i][7]);
    }
#undef LOAD_TILE
#undef STORE_TILE
}

// ---------------------------------------------------------------------------
// Persistent recurrence v9 = v6 (proven: coherent relaxed scalar h ping-pong,
// no fences, group-local flag barrier, W-in-LDS, c-in-registers, xg prefetch)
// with ONE change: microtile 4 batches x 4 gates per lane at 128 threads
// (2 waves). Per kk-iter 8 ds_read_b128 feed 64 lane-fma (was 6 per 32):
// ds_read per step/CU 3072 -> 2048 — the measured LDS-pipe bottleneck.
// No inline asm. Strict ascending-k fp32 fma chains — bit-identical numerics.
__global__ __launch_bounds__(128) void lstm_persist(
    const float* __restrict__ w_hh,   // [2048][512]
    const float* __restrict__ b_ih,   // [2048]
    const float* __restrict__ b_hh)   // [2048]
{
    extern __shared__ float smem[];
    float* __restrict__ Wl = smem;             // [64][WSTR]
    float* __restrict__ Hl = smem + LDS_WF;    // [2][32][HSTR]

    const int tid = threadIdx.x;
    const int grp = blockIdx.x & 7;            // batch group (XCD-near)
    const int jb  = blockIdx.x >> 3;           // j-slice within group 0..31
    const int j0 = jb * 16;
    const int b0 = grp * 32;

    // ---- one-time W tile load (128 threads): rows q*16+jl, full K ----
    {
        const int wr = tid >> 1;               // 0..63
        const int wf = tid & 1;
        const int wq = wr >> 4, wjl = wr & 15;
        const float* __restrict__ Wrow = w_hh + (size_t)(wq * NH + j0 + wjl) * NH;
        for (int kb = 0; kb < 512; kb += 128) {
            #pragma unroll
            for (int i = 0; i < 16; ++i) {
                float4 v = *(const float4*)(Wrow + kb + (wf + 2 * i) * 4);
                *(float4*)(&Wl[wr * WSTR + kb + (wf + 2 * i) * 4]) = v;
            }
        }
    }

    // microkernel / staging maps
    const int jj = tid & 15;                   // j col 0..15
    const int bg = tid >> 4;                   // batch quad 0..7 (4 batches each)
    const int hr = tid >> 2;                   // H stage row 0..31
    const int hc4 = tid & 3;                   // H stage 16-float col group

    // biases hoisted (same values every step)
    float bi[4], bh[4];
    #pragma unroll
    for (int q = 0; q < 4; ++q) {
        const int g = q * NH + j0 + jj;
        bi[q] = b_ih[g];
        bh[q] = b_hh[g];
    }

    float cc[4] = {0.f, 0.f, 0.f, 0.f};        // cell state in registers, all t

    // flag bookkeeping (group-local)
    int* __restrict__ my_flag   = &g_flags[(size_t)blockIdx.x * FLAG_STRIDE];
    int* __restrict__ poll_flag = (tid < 32)
        ? &g_flags[(size_t)((tid << 3) | grp) * FLAG_STRIDE] : nullptr;

    // xg for step 0 (original layout, plain loads — proven)
    float xgc[4][4];
    #pragma unroll
    for (int m = 0; m < 4; ++m)
        #pragma unroll
        for (int q = 0; q < 4; ++q)
            xgc[m][q] = g_xg[((size_t)b0 + bg * 4 + m) * NG + q * NH + j0 + jj];

    for (int t = 0; t < NT; ++t) {
        float acc[4][4];
        #pragma unroll
        for (int m = 0; m < 4; ++m)
            #pragma unroll
            for (int q = 0; q < 4; ++q) acc[m][q] = 0.f;

        const float* h_in = (t & 1) ? g_h1 : g_h0;
        const float* Hrow = h_in + (size_t)(b0 + hr) * NH + hc4 * 16;

        float hreg[16];
        // coherent scalar loads (proven v6): bypass L1/L2, read L3-valid h
        auto hload = [&](int kb) {
            #pragma unroll
            for (int u = 0; u < 16; ++u)
                hreg[u] = __hip_atomic_load(&Hrow[kb + u],
                                            __ATOMIC_RELAXED, __HIP_MEMORY_SCOPE_AGENT);
        };
        auto hstore = [&](int buf) {
            float* d = &Hl[buf * 32 * HSTR + hr * HSTR + hc4 * 16];
            *(f32x4*)(d)      = *(f32x4*)(&hreg[0]);
            *(f32x4*)(d + 4)  = *(f32x4*)(&hreg[4]);
            *(f32x4*)(d + 8)  = *(f32x4*)(&hreg[8]);
            *(f32x4*)(d + 12) = *(f32x4*)(&hreg[12]);
        };
        auto mk = [&](int buf, int kc) {
            const float* Hb = &Hl[buf * 32 * HSTR + bg * 4 * HSTR];
            const float* Wb = &Wl[jj * WSTR + kc];
            #pragma unroll
            for (int kk = 0; kk < 64; kk += 4) {
                const float4 hv0 = *(const float4*)(Hb + 0 * HSTR + kk);
                const float4 hv1 = *(const float4*)(Hb + 1 * HSTR + kk);
                const float4 hv2 = *(const float4*)(Hb + 2 * HSTR + kk);
                const float4 hv3 = *(const float4*)(Hb + 3 * HSTR + kk);
                #pragma unroll
                for (int q = 0; q < 4; ++q) {
                    const float4 w4 = *(const float4*)(Wb + q * 16 * WSTR + kk);
                    float a0 = acc[0][q], a1 = acc[1][q], a2 = acc[2][q], a3 = acc[3][q];
                    a0 = fmaf(hv0.x, w4.x, a0); a1 = fmaf(hv1.x, w4.x, a1);
                    a2 = fmaf(hv2.x, w4.x, a2); a3 = fmaf(hv3.x, w4.x, a3);
                    a0 = fmaf(hv0.y, w4.y, a0); a1 = fmaf(hv1.y, w4.y, a1);
                    a2 = fmaf(hv2.y, w4.y, a2); a3 = fmaf(hv3.y, w4.y, a3);
                    a0 = fmaf(hv0.z, w4.z, a0); a1 = fmaf(hv1.z, w4.z, a1);
                    a2 = fmaf(hv2.z, w4.z, a2); a3 = fmaf(hv3.z, w4.z, a3);
                    a0 = fmaf(hv0.w, w4.w, a0); a1 = fmaf(hv1.w, w4.w, a1);
                    a2 = fmaf(hv2.w, w4.w, a2); a3 = fmaf(hv3.w, w4.w, a3);
                    acc[0][q] = a0; acc[1][q] = a1; acc[2][q] = a2; acc[3][q] = a3;
                }
            }
        };

        hload(0);

        // prefetch NEXT step's xg (no dependence on h) — completes under compute
        float xgn[4][4];
        {
            const int tp = (t < NT - 1) ? t + 1 : t;   // last step: dummy (valid addr)
            const size_t base = ((size_t)tp * NB + b0 + bg * 4) * NG + j0 + jj;
            #pragma unroll
            for (int m = 0; m < 4; ++m)
                #pragma unroll
                for (int q = 0; q < 4; ++q)
                    xgn[m][q] = g_xg[base + (size_t)m * NG + (size_t)q * NH];
        }

        hstore(0);
        __syncthreads();
        for (int tc = 0; tc < 7; ++tc) {
            hload((tc + 1) * 64);
            mk(tc & 1, tc * 64);
            hstore((tc + 1) & 1);
            __syncthreads();
        }
        mk(1, 448);

        // gates: ((xg + b_ih) + hW) + b_hh — reference grouping, all fp32
        float* hout = ((t & 1) ? g_h0 : g_h1) + (size_t)(b0 + bg * 4) * NH + j0 + jj;
        #pragma unroll
        for (int m = 0; m < 4; ++m) {
            float s[4];
            #pragma unroll
            for (int q = 0; q < 4; ++q) {
                const float gate = ((xgc[m][q] + bi[q]) + acc[m][q]) + bh[q];
                s[q] = (gate >= 0.0f) ? 1.f : 0.f;
            }
            cc[m] = s[1] * cc[m] + s[0] * s[2];   // c = f*c + i*g (exact int)
            // coherent store: lands at L3, visible to group siblings w/o fences
            __hip_atomic_store(hout + (size_t)m * NH, cc[m] * s[3],
                               __ATOMIC_RELAXED, __HIP_MEMORY_SCOPE_AGENT);
        }

        // rotate prefetched xg into place
        #pragma unroll
        for (int m = 0; m < 4; ++m)
            #pragma unroll
            for (int q = 0; q < 4; ++q) xgc[m][q] = xgn[m][q];

        // group-local barrier (32 blocks), skip after last step.
        // __syncthreads drains vmcnt(0) -> coherent h stores are at L3;
        // then a single relaxed flag store; relaxed polls; NO fences.
        if (t != NT - 1) {
            __syncthreads();
            if (tid == 0)
                __hip_atomic_store(my_flag, t + 1,
                                   __ATOMIC_RELAXED, __HIP_MEMORY_SCOPE_AGENT);
            if (tid < 32) {
                while (__hip_atomic_load(poll_flag,
                                         __ATOMIC_RELAXED, __HIP_MEMORY_SCOPE_AGENT) < t + 1)
                    __builtin_amdgcn_s_sleep(1);
            }
            __syncthreads();
        }
    }
}

// ---------------------------------------------------------------------------
// logits = g_h0 @ fc_w^T + fc_b (strict f32 fma chains); stable f32 softmax.
__global__ __launch_bounds__(64) void final2(
    const float* __restrict__ fc_w,
    const float* __restrict__ fc_b,
    float* __restrict__ out)
{
    __shared__ float hl[NH];
    __shared__ float ls[10];
    const int b = blockIdx.x;
    const int tid = threadIdx.x;
    const float* __restrict__ hb = g_h0 + (size_t)b * NH;
    *(float4*)(&hl[tid * 4])       = *(const float4*)(hb + tid * 4);
    *(float4*)(&hl[256 + tid * 4]) = *(const float4*)(hb + 256 + tid * 4);
    __syncthreads();
    if (tid < 10) {
        float a = 0.f;
        const float* __restrict__ wr = fc_w + (size_t)tid * NH;
        for (int j = 0; j < NH; j += 4) {
            const float4 w4 = *(const float4*)(wr + j);
            a = fmaf(hl[j + 0], w4.x, a);
            a = fmaf(hl[j + 1], w4.y, a);
            a = fmaf(hl[j + 2], w4.z, a);
            a = fmaf(hl[j + 3], w4.w, a);
        }
        ls[tid] = a + fc_b[tid];
    }
    __syncthreads();
    if (tid == 0) {
        float m = -3.4e38f;
        #pragma unroll
        for (int o = 0; o < 10; ++o) m = (ls[o] > m) ? ls[o] : m;
        float e[10], ssum = 0.f;
        #pragma unroll
        for (int o = 0; o < 10; ++o) { e[o] = expf(ls[o] - m); ssum += e[o]; }
        const float inv = 1.0f / ssum;
        #pragma unroll
        for (int o = 0; o < 10; ++o) out[b * 10 + o] = e[o] * inv;
    }
}

// ---------------------------------------------------------------------------
extern "C" void kernel_launch(void* const* d_in, const int* in_sizes, int n_in,
                              void* d_out, int out_size, void* d_ws, size_t ws_size,
                              hipStream_t stream) {
    const float* x    = (const float*)d_in[0];
    const float* w_ih = (const float*)d_in[1];
    const float* b_ih = (const float*)d_in[2];
    const float* w_hh = (const float*)d_in[3];
    const float* b_hh = (const float*)d_in[4];
    const float* fc_w = (const float*)d_in[5];
    const float* fc_b = (const float*)d_in[6];
    float* out = (float*)d_out;

    static bool attr_set = false;
    if (!attr_set) {
        hipFuncSetAttribute((const void*)lstm_persist,
                            hipFuncAttributeMaxDynamicSharedMemorySize, LDS_BYTES);
        attr_set = true;
    }

    zero_state<<<512, 256, 0, stream>>>();

    // Hoisted input projection: one parallel GEMM for all 128 timesteps.
    xg_gemm<<<4096, 256, 0, stream>>>(x, w_ih);

    // All 128 recurrent steps in ONE persistent kernel (1 block/CU, W in LDS,
    // 128 threads, 4bx4q microtile — LDS-read-throughput optimized).
    lstm_persist<<<256, 128, LDS_BYTES, stream>>>(w_hh, b_ih, b_hh);

    // NT=128 even: last step (t=127) wrote g_h0.
    final2<<<256, 64, 0, stream>>>(fc_w, fc_b, out);
}

// Round 10
// 2977.662 us; speedup vs baseline: 1.5506x; 1.5506x over previous
//
#include <hip/hip_runtime.h>
#include <math.h>

#define NB 256
#define NH 512
#define NIN 512
#define NT 128
#define NG 2048   // 4*H gate rows

typedef __attribute__((ext_vector_type(4))) float f32x4;

// Persistent state in module data segment — capture-safe, ws-independent.
__device__ float g_h0[NB * NH];
__device__ float g_h1[NB * NH];
// Hoisted input projection xg[t][b][g] = chain_k x[t][b][k]*w_ih[g][k]  (256 MB)
__device__ float g_xg[(size_t)NT * NB * NG];
// Per-(block,wave) barrier flags, one 128B line each (monotonic step values).
#define FLAG_STRIDE 32
__device__ int g_flags[256 * 4 * FLAG_STRIDE];

// LDS layout for the persistent kernel
#define WSTR 516                     // 512 + 4 pad  (stride%32==4 -> 2-way = free)
#define HSTR 68                      // 64 + 4 pad
#define LDS_WF (64 * WSTR)           // persistent W tile, floats
#define LDS_HF (2 * 32 * HSTR)       // double-buffered H chunk, floats
#define LDS_BYTES ((LDS_WF + LDS_HF) * 4)   // 149504 B < 160 KiB/CU

// ---------------------------------------------------------------------------
__global__ __launch_bounds__(256) void zero_state() {
    int i = blockIdx.x * 256 + threadIdx.x;   // grid 512*256 = NB*NH
    g_h0[i] = 0.f;
    if (i < 256 * 4 * FLAG_STRIDE) g_flags[i] = 0;
}

// ---------------------------------------------------------------------------
// xg = x @ w_ih^T  : M=NT*NB=32768, N=NG=2048, K=512.  (proven-exact original)
#define BM 128
#define BN 128
#define BK 16

__global__ __launch_bounds__(256, 2) void xg_gemm(
    const float* __restrict__ x,      // [M][512]
    const float* __restrict__ w_ih)   // [2048][512]
{
    __shared__ float As[2][BK][BM + 4];
    __shared__ float Bs[2][BK][BN + 4];

    const int tid = threadIdx.x;
    const int bm = blockIdx.x >> 4;
    const int bn = blockIdx.x & 15;
    const size_t m0 = (size_t)bm * BM;
    const int n0 = bn * BN;

    const int srow = tid >> 1;
    const int sc4  = (tid & 1) * 8;
    const float* __restrict__ Arow = x    + (m0 + srow) * NIN;
    const float* __restrict__ Brow = w_ih + (size_t)(n0 + srow) * NIN;

    const int tx = tid & 15;
    const int ty = tid >> 4;

    float acc[8][8];
    #pragma unroll
    for (int i = 0; i < 8; ++i)
        #pragma unroll
        for (int j = 0; j < 8; ++j) acc[i][j] = 0.f;

    float4 ar0, ar1, br0, br1;

#define LOAD_TILE(kb) do {                                   \
        ar0 = *(const float4*)(Arow + (kb) + sc4);           \
        ar1 = *(const float4*)(Arow + (kb) + sc4 + 4);       \
        br0 = *(const float4*)(Brow + (kb) + sc4);           \
        br1 = *(const float4*)(Brow + (kb) + sc4 + 4);       \
    } while (0)

#define STORE_TILE(buf) do {                                             \
        As[buf][sc4+0][srow] = ar0.x; As[buf][sc4+1][srow] = ar0.y;      \
        As[buf][sc4+2][srow] = ar0.z; As[buf][sc4+3][srow] = ar0.w;      \
        As[buf][sc4+4][srow] = ar1.x; As[buf][sc4+5][srow] = ar1.y;      \
        As[buf][sc4+6][srow] = ar1.z; As[buf][sc4+7][srow] = ar1.w;      \
        Bs[buf][sc4+0][srow] = br0.x; Bs[buf][sc4+1][srow] = br0.y;      \
        Bs[buf][sc4+2][srow] = br0.z; Bs[buf][sc4+3][srow] = br0.w;      \
        Bs[buf][sc4+4][srow] = br1.x; Bs[buf][sc4+5][srow] = br1.y;      \
        Bs[buf][sc4+6][srow] = br1.z; Bs[buf][sc4+7][srow] = br1.w;      \
    } while (0)

    auto mk = [&](int buf) {
        #pragma unroll
        for (int k = 0; k < BK; ++k) {
            const float4 a0 = *(const float4*)(&As[buf][k][ty * 4]);
            const float4 a1 = *(const float4*)(&As[buf][k][64 + ty * 4]);
            const float4 b0 = *(const float4*)(&Bs[buf][k][tx * 4]);
            const float4 b1 = *(const float4*)(&Bs[buf][k][64 + tx * 4]);
            const float av[8] = {a0.x, a0.y, a0.z, a0.w, a1.x, a1.y, a1.z, a1.w};
            const float bv[8] = {b0.x, b0.y, b0.z, b0.w, b1.x, b1.y, b1.z, b1.w};
            #pragma unroll
            for (int i = 0; i < 8; ++i)
                #pragma unroll
                for (int j = 0; j < 8; ++j)
                    acc[i][j] = fmaf(av[i], bv[j], acc[i][j]);
        }
    };

    LOAD_TILE(0);
    STORE_TILE(0);
    __syncthreads();
    for (int tt = 0; tt < 31; ++tt) {
        LOAD_TILE((tt + 1) * BK);
        mk(tt & 1);
        STORE_TILE((tt + 1) & 1);
        __syncthreads();
    }
    mk(1);

    #pragma unroll
    for (int i = 0; i < 8; ++i) {
        const int mr = (i < 4) ? (ty * 4 + i) : (64 + ty * 4 + i - 4);
        float* __restrict__ orow = g_xg + (m0 + mr) * NG + n0;
        *(float4*)(orow + tx * 4)      = make_float4(acc[i][0], acc[i][1], acc[i][2], acc[i][3]);
        *(float4*)(orow + 64 + tx * 4) = make_float4(acc[i][4], acc[i][5], acc[i][6], acc[i][7]);
    }
#undef LOAD_TILE
#undef STORE_TILE
}

// ---------------------------------------------------------------------------
// Persistent recurrence v10 = v6 compute (256 thr, 2b x 4q, proven 2400 us,
// absmax 0.0) made BARRIER-FREE:
//  - H staging is wave-private by v6's own maps (wave w stages rows [8w,8w+8)
//    and reads only those rows) -> same-wave LDS ordering via lgkmcnt alone;
//    all 8 per-step __syncthreads deleted; per-wave double-buffer counter.
//  - Cross-block dependency is wave-to-wave: per-(block,wave) flags. After
//    vmcnt(0) drain, lane 0 sets flag; lanes 0..31 relaxed-poll the 32
//    sibling blocks' wave-w flags; __all converges the wave. No fences.
// 4 waves/CU become independent pipelines: LDS, VALU and L3 phases of
// different waves overlap. Strict ascending-k fp32 fma chains — bit-identical.
__global__ __launch_bounds__(256) void lstm_persist(
    const float* __restrict__ w_hh,   // [2048][512]
    const float* __restrict__ b_ih,   // [2048]
    const float* __restrict__ b_hh)   // [2048]
{
    extern __shared__ float smem[];
    float* __restrict__ Wl = smem;             // [64][WSTR]
    float* __restrict__ Hl = smem + LDS_WF;    // [2][32][HSTR]

    const int tid = threadIdx.x;
    const int grp = blockIdx.x & 7;            // batch group (XCD-near)
    const int jb  = blockIdx.x >> 3;           // j-slice within group 0..31
    const int j0 = jb * 16;
    const int b0 = grp * 32;
    const int lane = tid & 63;
    const int wv   = tid >> 6;                 // wave 0..3

    // ---- one-time W tile load: rows q*16+jl (gate-major), full K ----
    {
        const int wr = tid >> 2;               // 0..63
        const int wf = tid & 3;
        const int wq = wr >> 4, wjl = wr & 15;
        const float* __restrict__ Wrow = w_hh + (size_t)(wq * NH + j0 + wjl) * NH;
        for (int kb = 0; kb < 512; kb += 128) {
            #pragma unroll
            for (int i = 0; i < 8; ++i) {
                float4 v = *(const float4*)(Wrow + kb + (wf + 4 * i) * 4);
                *(float4*)(&Wl[wr * WSTR + kb + (wf + 4 * i) * 4]) = v;
            }
        }
    }
    __syncthreads();                           // ONLY block-wide barrier (W ready)

    // microkernel / staging maps (identical to v6; wave-partitioned by design)
    const int jj = tid & 15;                   // j col
    const int bg = tid >> 4;                   // b pair 0..15 (wave w: 4w..4w+3)
    const int hr = tid >> 3;                   // H stage row 0..31 (wave w: 8w..8w+7)
    const int hc = tid & 7;                    // H stage float4 base

    // biases hoisted (same values every step)
    float bi[4], bh[4];
    #pragma unroll
    for (int q = 0; q < 4; ++q) {
        const int g = q * NH + j0 + jj;
        bi[q] = b_ih[g];
        bh[q] = b_hh[g];
    }

    float cc[2] = {0.f, 0.f};                  // cell state in registers, all t

    // per-wave flag bookkeeping
    int* __restrict__ my_flag = &g_flags[((size_t)blockIdx.x * 4 + wv) * FLAG_STRIDE];
    int* __restrict__ poll_flag =
        &g_flags[(((size_t)((lane & 31) << 3) | grp) * 4 + wv) * FLAG_STRIDE];

    // xg for step 0
    float xgc[2][4];
    {
        const size_t base = ((size_t)b0 + bg * 2) * NG + j0 + jj;
        #pragma unroll
        for (int q = 0; q < 4; ++q) xgc[0][q] = g_xg[base + (size_t)q * NH];
        #pragma unroll
        for (int q = 0; q < 4; ++q) xgc[1][q] = g_xg[base + NG + (size_t)q * NH];
    }

    for (int t = 0; t < NT; ++t) {
        float acc[2][4];
        #pragma unroll
        for (int ib = 0; ib < 2; ++ib)
            #pragma unroll
            for (int q = 0; q < 4; ++q) acc[ib][q] = 0.f;

        const float* h_in = (t & 1) ? g_h1 : g_h0;
        const float* Hrow = h_in + (size_t)(b0 + hr) * NH;

        float hreg[8];
        // coherent scalar loads (proven v6): bypass L1/L2, read L3-valid h
        auto hload = [&](int kb) {
            #pragma unroll
            for (int u = 0; u < 4; ++u)
                hreg[u] = __hip_atomic_load(&Hrow[kb + hc * 4 + u],
                                            __ATOMIC_RELAXED, __HIP_MEMORY_SCOPE_AGENT);
            #pragma unroll
            for (int u = 0; u < 4; ++u)
                hreg[4 + u] = __hip_atomic_load(&Hrow[kb + (hc + 8) * 4 + u],
                                                __ATOMIC_RELAXED, __HIP_MEMORY_SCOPE_AGENT);
        };
        auto hstore = [&](int buf) {
            float* d = &Hl[buf * 32 * HSTR + hr * HSTR + hc * 4];
            *(f32x4*)(d)     = *(f32x4*)(&hreg[0]);
            float* d2 = &Hl[buf * 32 * HSTR + hr * HSTR + (hc + 8) * 4];
            *(f32x4*)(d2)    = *(f32x4*)(&hreg[4]);
        };
        auto mk = [&](int buf, int kc) {
            #pragma unroll
            for (int kk = 0; kk < 64; kk += 4) {
                const float4 h0v = *(const float4*)(&Hl[buf * 32 * HSTR + (bg * 2 + 0) * HSTR + kk]);
                const float4 h1v = *(const float4*)(&Hl[buf * 32 * HSTR + (bg * 2 + 1) * HSTR + kk]);
                #pragma unroll
                for (int q = 0; q < 4; ++q) {
                    const float4 w4 = *(const float4*)(&Wl[(q * 16 + jj) * WSTR + kc + kk]);
                    float a0 = acc[0][q], a1 = acc[1][q];
                    a0 = fmaf(h0v.x, w4.x, a0); a1 = fmaf(h1v.x, w4.x, a1);
                    a0 = fmaf(h0v.y, w4.y, a0); a1 = fmaf(h1v.y, w4.y, a1);
                    a0 = fmaf(h0v.z, w4.z, a0); a1 = fmaf(h1v.z, w4.z, a1);
                    a0 = fmaf(h0v.w, w4.w, a0); a1 = fmaf(h1v.w, w4.w, a1);
                    acc[0][q] = a0; acc[1][q] = a1;
                }
            }
        };

        hload(0);

        // prefetch NEXT step's xg (no dependence on h) — completes under compute
        float xgn[2][4];
        {
            const int tp = (t < NT - 1) ? t + 1 : t;   // last step: dummy (valid addr)
            const size_t base = ((size_t)tp * NB + b0 + bg * 2) * NG + j0 + jj;
            #pragma unroll
            for (int q = 0; q < 4; ++q) xgn[0][q] = g_xg[base + (size_t)q * NH];
            #pragma unroll
            for (int q = 0; q < 4; ++q) xgn[1][q] = g_xg[base + NG + (size_t)q * NH];
        }

        // wave-private chunk pipeline — NO barriers (same-wave LDS ordering
        // is by lgkmcnt; wave w touches only rows [8w,8w+8) of each buffer)
        hstore(0);
        for (int tc = 0; tc < 7; ++tc) {
            hload((tc + 1) * 64);
            mk(tc & 1, tc * 64);
            hstore((tc + 1) & 1);
        }
        mk(1, 448);

        // gates: ((xg + b_ih) + hW) + b_hh — reference grouping, all fp32
        float* hout = ((t & 1) ? g_h0 : g_h1) + (size_t)b0 * NH;
        #pragma unroll
        for (int ib = 0; ib < 2; ++ib) {
            float s[4];
            #pragma unroll
            for (int q = 0; q < 4; ++q) {
                const float gate = ((xgc[ib][q] + bi[q]) + acc[ib][q]) + bh[q];
                s[q] = (gate >= 0.0f) ? 1.f : 0.f;
            }
            cc[ib] = s[1] * cc[ib] + s[0] * s[2];    // c = f*c + i*g (exact int)
            // coherent store: lands at L3, visible to sibling wave-w w/o fences
            __hip_atomic_store(hout + (size_t)(bg * 2 + ib) * NH + j0 + jj,
                               cc[ib] * s[3],
                               __ATOMIC_RELAXED, __HIP_MEMORY_SCOPE_AGENT);
        }

        // rotate prefetched xg into place
        #pragma unroll
        for (int ib = 0; ib < 2; ++ib)
            #pragma unroll
            for (int q = 0; q < 4; ++q) xgc[ib][q] = xgn[ib][q];

        // per-wave cross-block sync (skip after last step):
        // drain h stores to L3, publish flag, poll 32 sibling wave-w flags.
        if (t != NT - 1) {
            asm volatile("s_waitcnt vmcnt(0)" ::: "memory");
            if (lane == 0)
                __hip_atomic_store(my_flag, t + 1,
                                   __ATOMIC_RELAXED, __HIP_MEMORY_SCOPE_AGENT);
            const int need = t + 1;
            while (true) {
                const int v = (lane < 32)
                    ? __hip_atomic_load(poll_flag, __ATOMIC_RELAXED, __HIP_MEMORY_SCOPE_AGENT)
                    : need;
                if (__all(v >= need)) break;
                __builtin_amdgcn_s_sleep(1);
            }
        }
    }
}

// ---------------------------------------------------------------------------
// logits = g_h0 @ fc_w^T + fc_b (strict f32 fma chains); stable f32 softmax.
__global__ __launch_bounds__(64) void final2(
    const float* __restrict__ fc_w,
    const float* __restrict__ fc_b,
    float* __restrict__ out)
{
    __shared__ float hl[NH];
    __shared__ float ls[10];
    const int b = blockIdx.x;
    const int tid = threadIdx.x;
    const float* __restrict__ hb = g_h0 + (size_t)b * NH;
    *(float4*)(&hl[tid * 4])       = *(const float4*)(hb + tid * 4);
    *(float4*)(&hl[256 + tid * 4]) = *(const float4*)(hb + 256 + tid * 4);
    __syncthreads();
    if (tid < 10) {
        float a = 0.f;
        const float* __restrict__ wr = fc_w + (size_t)tid * NH;
        for (int j = 0; j < NH; j += 4) {
            const float4 w4 = *(const float4*)(wr + j);
            a = fmaf(hl[j + 0], w4.x, a);
            a = fmaf(hl[j + 1], w4.y, a);
            a = fmaf(hl[j + 2], w4.z, a);
            a = fmaf(hl[j + 3], w4.w, a);
        }
        ls[tid] = a + fc_b[tid];
    }
    __syncthreads();
    if (tid == 0) {
        float m = -3.4e38f;
        #pragma unroll
        for (int o = 0; o < 10; ++o) m = (ls[o] > m) ? ls[o] : m;
        float e[10], ssum = 0.f;
        #pragma unroll
        for (int o = 0; o < 10; ++o) { e[o] = expf(ls[o] - m); ssum += e[o]; }
        const float inv = 1.0f / ssum;
        #pragma unroll
        for (int o = 0; o < 10; ++o) out[b * 10 + o] = e[o] * inv;
    }
}

// ---------------------------------------------------------------------------
extern "C" void kernel_launch(void* const* d_in, const int* in_sizes, int n_in,
                              void* d_out, int out_size, void* d_ws, size_t ws_size,
                              hipStream_t stream) {
    const float* x    = (const float*)d_in[0];
    const float* w_ih = (const float*)d_in[1];
    const float* b_ih = (const float*)d_in[2];
    const float* w_hh = (const float*)d_in[3];
    const float* b_hh = (const float*)d_in[4];
    const float* fc_w = (const float*)d_in[5];
    const float* fc_b = (const float*)d_in[6];
    float* out = (float*)d_out;

    static bool attr_set = false;
    if (!attr_set) {
        hipFuncSetAttribute((const void*)lstm_persist,
                            hipFuncAttributeMaxDynamicSharedMemorySize, LDS_BYTES);
        attr_set = true;
    }

    zero_state<<<512, 256, 0, stream>>>();

    // Hoisted input projection: one parallel GEMM for all 128 timesteps.
    xg_gemm<<<4096, 256, 0, stream>>>(x, w_ih);

    // All 128 recurrent steps in ONE persistent kernel (1 block/CU, W in LDS,
    // barrier-free wave pipelines with per-wave cross-block flags).
    lstm_persist<<<256, 256, LDS_BYTES, stream>>>(w_hh, b_ih, b_hh);

    // NT=128 even: last step (t=127) wrote g_h0.
    final2<<<256, 64, 0, stream>>>(fc_w, fc_b, out);
}

// Round 11
// 2904.186 us; speedup vs baseline: 1.5898x; 1.0253x over previous
//
#include <hip/hip_runtime.h>
#include <math.h>

#define NB 256
#define NH 512
#define NIN 512
#define NT 128
#define NG 2048   // 4*H gate rows

typedef __attribute__((ext_vector_type(4))) float f32x4;

// Persistent state in module data segment — capture-safe, ws-independent.
__device__ float g_h0[NB * NH];
__device__ float g_h1[NB * NH];
// Hoisted input projection xg[t][b][g] = chain_k x[t][b][k]*w_ih[g][k]  (256 MB)
__device__ float g_xg[(size_t)NT * NB * NG];
// Per-(block,wave) barrier flags, one 128B line each (monotonic step values).
#define FLAG_STRIDE 32
__device__ int g_flags[256 * 4 * FLAG_STRIDE];

// LDS layout for the persistent kernel
#define WSTR 516                     // 512 + 4 pad  (stride%32==4 -> 2-way = free)
#define HSTR 68                      // 64 + 4 pad
#define LDS_WF (64 * WSTR)           // persistent W tile, floats
#define LDS_HF (2 * 32 * HSTR)       // double-buffered H chunk, floats
#define LDS_BYTES ((LDS_WF + LDS_HF) * 4)   // 149504 B < 160 KiB/CU

// ---------------------------------------------------------------------------
__global__ __launch_bounds__(256) void zero_state() {
    int i = blockIdx.x * 256 + threadIdx.x;   // grid 512*256 = NB*NH
    g_h0[i] = 0.f;
    if (i < 256 * 4 * FLAG_STRIDE) g_flags[i] = 0;
}

// ---------------------------------------------------------------------------
// xg = x @ w_ih^T  : M=NT*NB=32768, N=NG=2048, K=512.
// v11: microtile widened 8x8 -> 8m x 16n (BN=256): 6 ds_read_b128 per k per
// thread feed 128 fma (was 4 per 64) — 25% fewer LDS insts per flop, the
// measured overhead above the 437 us fma floor. 50 KB LDS, 2 blocks/CU.
// Per-output chains unchanged: one fma per k, k strictly ascending.
#define BM 128
#define BN 256
#define BK 16

__global__ __launch_bounds__(256, 2) void xg_gemm(
    const float* __restrict__ x,      // [M][512]
    const float* __restrict__ w_ih)   // [2048][512]
{
    __shared__ float As[2][BK][BM + 4];   // k-major, 132 stride
    __shared__ float Bs[2][BK][BN + 4];   // k-major, 260 stride

    const int tid = threadIdx.x;
    const int bm = blockIdx.x >> 3;       // 256 m-blocks
    const int bn = blockIdx.x & 7;        // 8 n-blocks
    const size_t m0 = (size_t)bm * BM;
    const int n0 = bn * BN;

    // staging maps: A = 128 rows x 16 k (8 floats/thread);
    //               B = 256 rows x 16 k (16 floats/thread)
    const int arow = tid >> 1;
    const int ac   = (tid & 1) * 8;
    const int brow = tid;
    const float* __restrict__ Arow = x    + (m0 + arow) * NIN;
    const float* __restrict__ Brow = w_ih + (size_t)(n0 + brow) * NIN;

    // microkernel: tx = n-group (16), ty = m-group (16)
    const int tx = tid & 15;
    const int ty = tid >> 4;

    float acc[8][16];
    #pragma unroll
    for (int i = 0; i < 8; ++i)
        #pragma unroll
        for (int j = 0; j < 16; ++j) acc[i][j] = 0.f;

    float4 ar0, ar1, br0, br1, br2, br3;

#define LOAD_TILE(kb) do {                                   \
        ar0 = *(const float4*)(Arow + (kb) + ac);            \
        ar1 = *(const float4*)(Arow + (kb) + ac + 4);        \
        br0 = *(const float4*)(Brow + (kb));                 \
        br1 = *(const float4*)(Brow + (kb) + 4);             \
        br2 = *(const float4*)(Brow + (kb) + 8);             \
        br3 = *(const float4*)(Brow + (kb) + 12);            \
    } while (0)

#define STORE_TILE(buf) do {                                             \
        As[buf][ac+0][arow] = ar0.x; As[buf][ac+1][arow] = ar0.y;        \
        As[buf][ac+2][arow] = ar0.z; As[buf][ac+3][arow] = ar0.w;        \
        As[buf][ac+4][arow] = ar1.x; As[buf][ac+5][arow] = ar1.y;        \
        As[buf][ac+6][arow] = ar1.z; As[buf][ac+7][arow] = ar1.w;        \
        Bs[buf][ 0][brow] = br0.x; Bs[buf][ 1][brow] = br0.y;            \
        Bs[buf][ 2][brow] = br0.z; Bs[buf][ 3][brow] = br0.w;            \
        Bs[buf][ 4][brow] = br1.x; Bs[buf][ 5][brow] = br1.y;            \
        Bs[buf][ 6][brow] = br1.z; Bs[buf][ 7][brow] = br1.w;            \
        Bs[buf][ 8][brow] = br2.x; Bs[buf][ 9][brow] = br2.y;            \
        Bs[buf][10][brow] = br2.z; Bs[buf][11][brow] = br2.w;            \
        Bs[buf][12][brow] = br3.x; Bs[buf][13][brow] = br3.y;            \
        Bs[buf][14][brow] = br3.z; Bs[buf][15][brow] = br3.w;            \
    } while (0)

    auto mk = [&](int buf) {
        #pragma unroll
        for (int k = 0; k < BK; ++k) {
            const float4 a0 = *(const float4*)(&As[buf][k][ty * 4]);
            const float4 a1 = *(const float4*)(&As[buf][k][64 + ty * 4]);
            const float4 b0 = *(const float4*)(&Bs[buf][k][tx * 4]);
            const float4 b1 = *(const float4*)(&Bs[buf][k][64 + tx * 4]);
            const float4 b2 = *(const float4*)(&Bs[buf][k][128 + tx * 4]);
            const float4 b3 = *(const float4*)(&Bs[buf][k][192 + tx * 4]);
            const float av[8]  = {a0.x, a0.y, a0.z, a0.w, a1.x, a1.y, a1.z, a1.w};
            const float bv[16] = {b0.x, b0.y, b0.z, b0.w, b1.x, b1.y, b1.z, b1.w,
                                  b2.x, b2.y, b2.z, b2.w, b3.x, b3.y, b3.z, b3.w};
            #pragma unroll
            for (int i = 0; i < 8; ++i)
                #pragma unroll
                for (int j = 0; j < 16; ++j)
                    acc[i][j] = fmaf(av[i], bv[j], acc[i][j]);  // one fma/k, ascending
        }
    };

    LOAD_TILE(0);
    STORE_TILE(0);
    __syncthreads();
    for (int tt = 0; tt < 31; ++tt) {
        LOAD_TILE((tt + 1) * BK);
        mk(tt & 1);
        STORE_TILE((tt + 1) & 1);
        __syncthreads();
    }
    mk(1);

    #pragma unroll
    for (int i = 0; i < 8; ++i) {
        const int mr = (i < 4) ? (ty * 4 + i) : (64 + ty * 4 + i - 4);
        float* __restrict__ orow = g_xg + (m0 + mr) * NG + n0;
        #pragma unroll
        for (int h = 0; h < 4; ++h)
            *(float4*)(orow + 64 * h + tx * 4) =
                make_float4(acc[i][h * 4 + 0], acc[i][h * 4 + 1],
                            acc[i][h * 4 + 2], acc[i][h * 4 + 3]);
    }
#undef LOAD_TILE
#undef STORE_TILE
}

// ---------------------------------------------------------------------------
// Persistent recurrence v10 (UNCHANGED — proven 2230 us, absmax 0.0):
// barrier-free wave pipelines, per-(block,wave) flags, W-in-LDS, c-in-regs,
// coherent relaxed h ping-pong, xg prefetch. Strict ascending-k fp32 chains.
__global__ __launch_bounds__(256) void lstm_persist(
    const float* __restrict__ w_hh,   // [2048][512]
    const float* __restrict__ b_ih,   // [2048]
    const float* __restrict__ b_hh)   // [2048]
{
    extern __shared__ float smem[];
    float* __restrict__ Wl = smem;             // [64][WSTR]
    float* __restrict__ Hl = smem + LDS_WF;    // [2][32][HSTR]

    const int tid = threadIdx.x;
    const int grp = blockIdx.x & 7;            // batch group (XCD-near)
    const int jb  = blockIdx.x >> 3;           // j-slice within group 0..31
    const int j0 = jb * 16;
    const int b0 = grp * 32;
    const int lane = tid & 63;
    const int wv   = tid >> 6;                 // wave 0..3

    // ---- one-time W tile load: rows q*16+jl (gate-major), full K ----
    {
        const int wr = tid >> 2;               // 0..63
        const int wf = tid & 3;
        const int wq = wr >> 4, wjl = wr & 15;
        const float* __restrict__ Wrow = w_hh + (size_t)(wq * NH + j0 + wjl) * NH;
        for (int kb = 0; kb < 512; kb += 128) {
            #pragma unroll
            for (int i = 0; i < 8; ++i) {
                float4 v = *(const float4*)(Wrow + kb + (wf + 4 * i) * 4);
                *(float4*)(&Wl[wr * WSTR + kb + (wf + 4 * i) * 4]) = v;
            }
        }
    }
    __syncthreads();                           // ONLY block-wide barrier (W ready)

    // microkernel / staging maps (wave-partitioned by design)
    const int jj = tid & 15;                   // j col
    const int bg = tid >> 4;                   // b pair 0..15 (wave w: 4w..4w+3)
    const int hr = tid >> 3;                   // H stage row 0..31 (wave w: 8w..8w+7)
    const int hc = tid & 7;                    // H stage float4 base

    // biases hoisted (same values every step)
    float bi[4], bh[4];
    #pragma unroll
    for (int q = 0; q < 4; ++q) {
        const int g = q * NH + j0 + jj;
        bi[q] = b_ih[g];
        bh[q] = b_hh[g];
    }

    float cc[2] = {0.f, 0.f};                  // cell state in registers, all t

    // per-wave flag bookkeeping
    int* __restrict__ my_flag = &g_flags[((size_t)blockIdx.x * 4 + wv) * FLAG_STRIDE];
    int* __restrict__ poll_flag =
        &g_flags[(((size_t)((lane & 31) << 3) | grp) * 4 + wv) * FLAG_STRIDE];

    // xg for step 0
    float xgc[2][4];
    {
        const size_t base = ((size_t)b0 + bg * 2) * NG + j0 + jj;
        #pragma unroll
        for (int q = 0; q < 4; ++q) xgc[0][q] = g_xg[base + (size_t)q * NH];
        #pragma unroll
        for (int q = 0; q < 4; ++q) xgc[1][q] = g_xg[base + NG + (size_t)q * NH];
    }

    for (int t = 0; t < NT; ++t) {
        float acc[2][4];
        #pragma unroll
        for (int ib = 0; ib < 2; ++ib)
            #pragma unroll
            for (int q = 0; q < 4; ++q) acc[ib][q] = 0.f;

        const float* h_in = (t & 1) ? g_h1 : g_h0;
        const float* Hrow = h_in + (size_t)(b0 + hr) * NH;

        float hreg[8];
        // coherent scalar loads (proven v6): bypass L1/L2, read L3-valid h
        auto hload = [&](int kb) {
            #pragma unroll
            for (int u = 0; u < 4; ++u)
                hreg[u] = __hip_atomic_load(&Hrow[kb + hc * 4 + u],
                                            __ATOMIC_RELAXED, __HIP_MEMORY_SCOPE_AGENT);
            #pragma unroll
            for (int u = 0; u < 4; ++u)
                hreg[4 + u] = __hip_atomic_load(&Hrow[kb + (hc + 8) * 4 + u],
                                                __ATOMIC_RELAXED, __HIP_MEMORY_SCOPE_AGENT);
        };
        auto hstore = [&](int buf) {
            float* d = &Hl[buf * 32 * HSTR + hr * HSTR + hc * 4];
            *(f32x4*)(d)     = *(f32x4*)(&hreg[0]);
            float* d2 = &Hl[buf * 32 * HSTR + hr * HSTR + (hc + 8) * 4];
            *(f32x4*)(d2)    = *(f32x4*)(&hreg[4]);
        };
        auto mk = [&](int buf, int kc) {
            #pragma unroll
            for (int kk = 0; kk < 64; kk += 4) {
                const float4 h0v = *(const float4*)(&Hl[buf * 32 * HSTR + (bg * 2 + 0) * HSTR + kk]);
                const float4 h1v = *(const float4*)(&Hl[buf * 32 * HSTR + (bg * 2 + 1) * HSTR + kk]);
                #pragma unroll
                for (int q = 0; q < 4; ++q) {
                    const float4 w4 = *(const float4*)(&Wl[(q * 16 + jj) * WSTR + kc + kk]);
                    float a0 = acc[0][q], a1 = acc[1][q];
                    a0 = fmaf(h0v.x, w4.x, a0); a1 = fmaf(h1v.x, w4.x, a1);
                    a0 = fmaf(h0v.y, w4.y, a0); a1 = fmaf(h1v.y, w4.y, a1);
                    a0 = fmaf(h0v.z, w4.z, a0); a1 = fmaf(h1v.z, w4.z, a1);
                    a0 = fmaf(h0v.w, w4.w, a0); a1 = fmaf(h1v.w, w4.w, a1);
                    acc[0][q] = a0; acc[1][q] = a1;
                }
            }
        };

        hload(0);

        // prefetch NEXT step's xg (no dependence on h) — completes under compute
        float xgn[2][4];
        {
            const int tp = (t < NT - 1) ? t + 1 : t;   // last step: dummy (valid addr)
            const size_t base = ((size_t)tp * NB + b0 + bg * 2) * NG + j0 + jj;
            #pragma unroll
            for (int q = 0; q < 4; ++q) xgn[0][q] = g_xg[base + (size_t)q * NH];
            #pragma unroll
            for (int q = 0; q < 4; ++q) xgn[1][q] = g_xg[base + NG + (size_t)q * NH];
        }

        // wave-private chunk pipeline — NO barriers (same-wave LDS ordering
        // is by lgkmcnt; wave w touches only rows [8w,8w+8) of each buffer)
        hstore(0);
        for (int tc = 0; tc < 7; ++tc) {
            hload((tc + 1) * 64);
            mk(tc & 1, tc * 64);
            hstore((tc + 1) & 1);
        }
        mk(1, 448);

        // gates: ((xg + b_ih) + hW) + b_hh — reference grouping, all fp32
        float* hout = ((t & 1) ? g_h0 : g_h1) + (size_t)b0 * NH;
        #pragma unroll
        for (int ib = 0; ib < 2; ++ib) {
            float s[4];
            #pragma unroll
            for (int q = 0; q < 4; ++q) {
                const float gate = ((xgc[ib][q] + bi[q]) + acc[ib][q]) + bh[q];
                s[q] = (gate >= 0.0f) ? 1.f : 0.f;
            }
            cc[ib] = s[1] * cc[ib] + s[0] * s[2];    // c = f*c + i*g (exact int)
            // coherent store: lands at L3, visible to sibling wave-w w/o fences
            __hip_atomic_store(hout + (size_t)(bg * 2 + ib) * NH + j0 + jj,
                               cc[ib] * s[3],
                               __ATOMIC_RELAXED, __HIP_MEMORY_SCOPE_AGENT);
        }

        // rotate prefetched xg into place
        #pragma unroll
        for (int ib = 0; ib < 2; ++ib)
            #pragma unroll
            for (int q = 0; q < 4; ++q) xgc[ib][q] = xgn[ib][q];

        // per-wave cross-block sync (skip after last step):
        // drain h stores to L3, publish flag, poll 32 sibling wave-w flags.
        if (t != NT - 1) {
            asm volatile("s_waitcnt vmcnt(0)" ::: "memory");
            if (lane == 0)
                __hip_atomic_store(my_flag, t + 1,
                                   __ATOMIC_RELAXED, __HIP_MEMORY_SCOPE_AGENT);
            const int need = t + 1;
            while (true) {
                const int v = (lane < 32)
                    ? __hip_atomic_load(poll_flag, __ATOMIC_RELAXED, __HIP_MEMORY_SCOPE_AGENT)
                    : need;
                if (__all(v >= need)) break;
                __builtin_amdgcn_s_sleep(1);
            }
        }
    }
}

// ---------------------------------------------------------------------------
// logits = g_h0 @ fc_w^T + fc_b (strict f32 fma chains); stable f32 softmax.
__global__ __launch_bounds__(64) void final2(
    const float* __restrict__ fc_w,
    const float* __restrict__ fc_b,
    float* __restrict__ out)
{
    __shared__ float hl[NH];
    __shared__ float ls[10];
    const int b = blockIdx.x;
    const int tid = threadIdx.x;
    const float* __restrict__ hb = g_h0 + (size_t)b * NH;
    *(float4*)(&hl[tid * 4])       = *(const float4*)(hb + tid * 4);
    *(float4*)(&hl[256 + tid * 4]) = *(const float4*)(hb + 256 + tid * 4);
    __syncthreads();
    if (tid < 10) {
        float a = 0.f;
        const float* __restrict__ wr = fc_w + (size_t)tid * NH;
        for (int j = 0; j < NH; j += 4) {
            const float4 w4 = *(const float4*)(wr + j);
            a = fmaf(hl[j + 0], w4.x, a);
            a = fmaf(hl[j + 1], w4.y, a);
            a = fmaf(hl[j + 2], w4.z, a);
            a = fmaf(hl[j + 3], w4.w, a);
        }
        ls[tid] = a + fc_b[tid];
    }
    __syncthreads();
    if (tid == 0) {
        float m = -3.4e38f;
        #pragma unroll
        for (int o = 0; o < 10; ++o) m = (ls[o] > m) ? ls[o] : m;
        float e[10], ssum = 0.f;
        #pragma unroll
        for (int o = 0; o < 10; ++o) { e[o] = expf(ls[o] - m); ssum += e[o]; }
        const float inv = 1.0f / ssum;
        #pragma unroll
        for (int o = 0; o < 10; ++o) out[b * 10 + o] = e[o] * inv;
    }
}

// ---------------------------------------------------------------------------
extern "C" void kernel_launch(void* const* d_in, const int* in_sizes, int n_in,
                              void* d_out, int out_size, void* d_ws, size_t ws_size,
                              hipStream_t stream) {
    const float* x    = (const float*)d_in[0];
    const float* w_ih = (const float*)d_in[1];
    const float* b_ih = (const float*)d_in[2];
    const float* w_hh = (const float*)d_in[3];
    const float* b_hh = (const float*)d_in[4];
    const float* fc_w = (const float*)d_in[5];
    const float* fc_b = (const float*)d_in[6];
    float* out = (float*)d_out;

    static bool attr_set = false;
    if (!attr_set) {
        hipFuncSetAttribute((const void*)lstm_persist,
                            hipFuncAttributeMaxDynamicSharedMemorySize, LDS_BYTES);
        attr_set = true;
    }

    zero_state<<<512, 256, 0, stream>>>();

    // Hoisted input projection: one parallel GEMM for all 128 timesteps.
    // v11: BM=128 x BN=256 tile, 8x16 microtile, 2 blocks/CU.
    xg_gemm<<<2048, 256, 0, stream>>>(x, w_ih);

    // All 128 recurrent steps in ONE persistent kernel (1 block/CU, W in LDS,
    // barrier-free wave pipelines with per-wave cross-block flags).
    lstm_persist<<<256, 256, LDS_BYTES, stream>>>(w_hh, b_ih, b_hh);

    // NT=128 even: last step (t=127) wrote g_h0.
    final2<<<256, 64, 0, stream>>>(fc_w, fc_b, out);
}